// Round 1
// baseline (340.292 us; speedup 1.0000x reference)
//
#include <hip/hip_runtime.h>
#include <cstdint>

#define NFEAT 4096
#define NHALF 2048
#define DDIM  512
#define QROWS 32768

typedef unsigned short u16;
typedef unsigned int   u32;
typedef unsigned long long u64;

typedef __bf16 bf16x8_t __attribute__((ext_vector_type(8)));
typedef float  f32x4_t  __attribute__((ext_vector_type(4)));

typedef const __attribute__((address_space(1))) void* gas_ptr;
typedef __attribute__((address_space(3))) void* las_ptr;

__device__ __forceinline__ u16 f2bf(float f) {
  u32 u = __float_as_uint(f);
  u32 r = u + 0x7FFFu + ((u >> 16) & 1u);
  return (u16)(r >> 16);
}

// monotonic unsigned encoding of float (no NaN/Inf expected)
__device__ __forceinline__ u32 fkey(float f) {
  u32 u = __float_as_uint(f);
  return (u & 0x80000000u) ? ~u : (u | 0x80000000u);
}

// ---------------- kernel 1: l2-normalize rows -> bf16 ----------------
// one wave per row; rows [0,4096) = features (z_i|z_j), [4096, 4096+32768) = queue
__global__ void k_norm(const float* __restrict__ zi, const float* __restrict__ zj,
                       const float* __restrict__ queue,
                       u16* __restrict__ featb, u16* __restrict__ queueb) {
  int gw = (int)((blockIdx.x * blockDim.x + threadIdx.x) >> 6);
  int lane = threadIdx.x & 63;
  const float* src; u16* dst;
  if (gw < NFEAT) {
    src = (gw < NHALF) ? (zi + (size_t)gw * DDIM) : (zj + (size_t)(gw - NHALF) * DDIM);
    dst = featb + (size_t)gw * DDIM;
  } else {
    int r = gw - NFEAT;
    src = queue + (size_t)r * DDIM;
    dst = queueb + (size_t)r * DDIM;
  }
  float4 v0 = reinterpret_cast<const float4*>(src)[lane * 2];
  float4 v1 = reinterpret_cast<const float4*>(src)[lane * 2 + 1];
  float ss = v0.x*v0.x + v0.y*v0.y + v0.z*v0.z + v0.w*v0.w
           + v1.x*v1.x + v1.y*v1.y + v1.z*v1.z + v1.w*v1.w;
  #pragma unroll
  for (int off = 32; off >= 1; off >>= 1) ss += __shfl_xor(ss, off);
  float inv = 1.0f / fmaxf(sqrtf(ss), 1e-12f);
  ushort4 o0, o1;
  o0.x = f2bf(v0.x * inv); o0.y = f2bf(v0.y * inv);
  o0.z = f2bf(v0.z * inv); o0.w = f2bf(v0.w * inv);
  o1.x = f2bf(v1.x * inv); o1.y = f2bf(v1.y * inv);
  o1.z = f2bf(v1.z * inv); o1.w = f2bf(v1.w * inv);
  reinterpret_cast<ushort4*>(dst)[lane * 2]     = o0;
  reinterpret_cast<ushort4*>(dst)[lane * 2 + 1] = o1;
}

// ---------------- GEMM common geometry ----------------
// BM=BN=128, BK=64, 256 threads = 4 waves (2x2), each wave 64x64 out (4x4 frags of 16x16)
#define BM 128
#define BN 128
#define BK 64

// ---------------- kernel 2: features @ queue^T with fused row-argmax ----------------
// grid = 32 row-tiles * 256 q-tiles; partials: part[row][qt*2+wc] packed u64
__global__ __launch_bounds__(256) void k_argmax_gemm(
    const u16* __restrict__ featb, const u16* __restrict__ queueb,
    u64* __restrict__ part) {
  __shared__ u16 As[BM * BK];
  __shared__ u16 Bs[BN * BK];
  const int tid = threadIdx.x;
  const int w = tid >> 6, lane = tid & 63;
  const int wr = w >> 1, wc = w & 1;
  const int mt = blockIdx.x & 31;
  const int qt = blockIdx.x >> 5;
  const int brow = mt * BM, bcol = qt * BN;
  const int srow = lane >> 3, scol = (lane & 7) * 8;
  const int lg = lane >> 4, li = lane & 15;

  f32x4_t acc[4][4] = {};

  for (int kt = 0; kt < DDIM; kt += BK) {
    __syncthreads();
    #pragma unroll
    for (int i = 0; i < 4; i++) {
      const int r0 = (w * 4 + i) * 8;
      const u16* ga = featb  + (size_t)(brow + r0 + srow) * DDIM + kt + scol;
      const u16* gb = queueb + (size_t)(bcol + r0 + srow) * DDIM + kt + scol;
      __builtin_amdgcn_global_load_lds((gas_ptr)ga, (las_ptr)&As[r0 * BK], 16, 0, 0);
      __builtin_amdgcn_global_load_lds((gas_ptr)gb, (las_ptr)&Bs[r0 * BK], 16, 0, 0);
    }
    __syncthreads();
    #pragma unroll
    for (int kk = 0; kk < 2; kk++) {
      bf16x8_t af[4], bfr[4];
      const int ko = kk * 32 + lg * 8;
      #pragma unroll
      for (int m = 0; m < 4; m++)
        af[m] = *reinterpret_cast<const bf16x8_t*>(&As[(wr*64 + m*16 + li) * BK + ko]);
      #pragma unroll
      for (int n = 0; n < 4; n++)
        bfr[n] = *reinterpret_cast<const bf16x8_t*>(&Bs[(wc*64 + n*16 + li) * BK + ko]);
      #pragma unroll
      for (int m = 0; m < 4; m++)
        #pragma unroll
        for (int n = 0; n < 4; n++)
          acc[m][n] = __builtin_amdgcn_mfma_f32_16x16x32_bf16(af[m], bfr[n], acc[m][n], 0, 0, 0);
    }
  }

  // epilogue: per-row argmax over this block's 128 cols
  #pragma unroll
  for (int m = 0; m < 4; m++) {
    #pragma unroll
    for (int j = 0; j < 4; j++) {
      u64 best = 0;
      #pragma unroll
      for (int n = 0; n < 4; n++) {
        float v = acc[m][n][j];
        u32 col = (u32)(bcol + wc*64 + n*16 + li);
        u64 key = ((u64)fkey(v) << 32) | (u64)(0xFFFFFFFFu - col);
        best = best > key ? best : key;
      }
      #pragma unroll
      for (int off = 1; off < 16; off <<= 1) {
        u64 o = __shfl_xor(best, off);
        best = best > o ? best : o;
      }
      if (li == 0) {
        int row = brow + wr*64 + m*16 + lg*4 + j;
        part[(size_t)row * 512 + (qt*2 + wc)] = best;
      }
    }
  }
}

// ---------------- kernel 3: reduce argmax partials -> nn_idx ----------------
__global__ void k_argmax_reduce(const u64* __restrict__ part, int* __restrict__ nnidx) {
  int row = (int)((blockIdx.x * blockDim.x + threadIdx.x) >> 6);
  int lane = threadIdx.x & 63;
  const u64* p = part + (size_t)row * 512;
  u64 best = 0;
  #pragma unroll
  for (int i = 0; i < 8; i++) { u64 v = p[lane * 8 + i]; best = best > v ? best : v; }
  #pragma unroll
  for (int off = 1; off < 64; off <<= 1) { u64 o = __shfl_xor(best, off); best = best > o ? best : o; }
  if (lane == 0) nnidx[row] = (int)(0xFFFFFFFFu - (u32)(best & 0xFFFFFFFFu));
}

// ---------------- kernel 4: sim = nn_feats @ features^T / T, fused lse partials + positives ----
// grid = 32 row-tiles * 32 col-tiles; lsep[row][ct*2+wc] = (max, sumexp)
__global__ __launch_bounds__(256) void k_sim_gemm(
    const u16* __restrict__ featb, const u16* __restrict__ queueb,
    const int* __restrict__ nnidx,
    float2* __restrict__ lsep, float* __restrict__ pos) {
  __shared__ u16 As[BM * BK];
  __shared__ u16 Bs[BN * BK];
  const int tid = threadIdx.x;
  const int w = tid >> 6, lane = tid & 63;
  const int wr = w >> 1, wc = w & 1;
  const int mt = blockIdx.x & 31;
  const int ct = blockIdx.x >> 5;
  const int brow = mt * BM, bcol = ct * BN;
  const int srow = lane >> 3, scol = (lane & 7) * 8;
  const int lg = lane >> 4, li = lane & 15;

  int ridx[4];
  #pragma unroll
  for (int i = 0; i < 4; i++) ridx[i] = nnidx[brow + (w*4 + i)*8 + srow];

  f32x4_t acc[4][4] = {};

  for (int kt = 0; kt < DDIM; kt += BK) {
    __syncthreads();
    #pragma unroll
    for (int i = 0; i < 4; i++) {
      const int r0 = (w * 4 + i) * 8;
      const u16* ga = queueb + (size_t)ridx[i] * DDIM + kt + scol;          // gathered NN rows
      const u16* gb = featb  + (size_t)(bcol + r0 + srow) * DDIM + kt + scol;
      __builtin_amdgcn_global_load_lds((gas_ptr)ga, (las_ptr)&As[r0 * BK], 16, 0, 0);
      __builtin_amdgcn_global_load_lds((gas_ptr)gb, (las_ptr)&Bs[r0 * BK], 16, 0, 0);
    }
    __syncthreads();
    #pragma unroll
    for (int kk = 0; kk < 2; kk++) {
      bf16x8_t af[4], bfr[4];
      const int ko = kk * 32 + lg * 8;
      #pragma unroll
      for (int m = 0; m < 4; m++)
        af[m] = *reinterpret_cast<const bf16x8_t*>(&As[(wr*64 + m*16 + li) * BK + ko]);
      #pragma unroll
      for (int n = 0; n < 4; n++)
        bfr[n] = *reinterpret_cast<const bf16x8_t*>(&Bs[(wc*64 + n*16 + li) * BK + ko]);
      #pragma unroll
      for (int m = 0; m < 4; m++)
        #pragma unroll
        for (int n = 0; n < 4; n++)
          acc[m][n] = __builtin_amdgcn_mfma_f32_16x16x32_bf16(af[m], bfr[n], acc[m][n], 0, 0, 0);
    }
  }

  // epilogue: scale by 1/T=2, capture positives, mask diag, per-row (max, sumexp) over 128 cols
  #pragma unroll
  for (int m = 0; m < 4; m++) {
    #pragma unroll
    for (int j = 0; j < 4; j++) {
      int row = brow + wr*64 + m*16 + lg*4 + j;
      float vals[4];
      float vmax = -3.0e38f;
      #pragma unroll
      for (int n = 0; n < 4; n++) {
        int col = bcol + wc*64 + n*16 + li;
        float v = acc[m][n][j] * 2.0f;
        if (col == (row ^ NHALF)) pos[row] = v;   // positive sample (unique writer)
        if (col == row) v = -1.0e30f;             // diag mask
        vals[n] = v;
        vmax = fmaxf(vmax, v);
      }
      float s = 0.f;
      #pragma unroll
      for (int n = 0; n < 4; n++) s += __expf(vals[n] - vmax);
      #pragma unroll
      for (int off = 1; off < 16; off <<= 1) {
        float mo = __shfl_xor(vmax, off);
        float so = __shfl_xor(s, off);
        float M = fmaxf(vmax, mo);
        s = s * __expf(vmax - M) + so * __expf(mo - M);
        vmax = M;
      }
      if (li == 0) lsep[(size_t)row * 64 + (ct*2 + wc)] = make_float2(vmax, s);
    }
  }
}

// ---------------- kernel 5: per-row logsumexp merge ----------------
__global__ void k_lse(const float2* __restrict__ lsep, float* __restrict__ lse) {
  int row = (int)((blockIdx.x * blockDim.x + threadIdx.x) >> 6);
  int lane = threadIdx.x & 63;
  float2 p = lsep[(size_t)row * 64 + lane];
  float m = p.x, s = p.y;
  #pragma unroll
  for (int off = 1; off < 64; off <<= 1) {
    float mo = __shfl_xor(m, off), so = __shfl_xor(s, off);
    float M = fmaxf(m, mo);
    s = s * __expf(m - M) + so * __expf(mo - M);
    m = M;
  }
  if (lane == 0) lse[row] = m + __logf(s);
}

// ---------------- kernel 6: final scalar ----------------
__global__ void k_final(const float* __restrict__ lse, const float* __restrict__ pos,
                        float* __restrict__ out) {
  __shared__ float red[4];
  int tid = threadIdx.x;
  float a = 0.f;
  for (int i = tid; i < NFEAT; i += 256) a += lse[i] - pos[i];
  #pragma unroll
  for (int off = 32; off >= 1; off >>= 1) a += __shfl_xor(a, off);
  if ((tid & 63) == 0) red[tid >> 6] = a;
  __syncthreads();
  if (tid == 0) out[0] = (red[0] + red[1] + red[2] + red[3]) / (float)NFEAT;
}

extern "C" void kernel_launch(void* const* d_in, const int* in_sizes, int n_in,
                              void* d_out, int out_size, void* d_ws, size_t ws_size,
                              hipStream_t stream) {
  const float* zi    = (const float*)d_in[0];
  const float* zj    = (const float*)d_in[1];
  const float* queue = (const float*)d_in[2];
  float* out = (float*)d_out;
  char* ws = (char*)d_ws;

  // ws layout (bytes):
  u16*    queueb = (u16*)(ws + 0);               // 32768*512*2 = 33554432
  u16*    featb  = (u16*)(ws + 33554432);        // 4096*512*2  = 4194304
  u64*    part   = (u64*)(ws + 37748736);        // 4096*512*8  = 16777216
  int*    nnidx  = (int*)(ws + 54525952);        // 4096*4      = 16384
  float2* lsep   = (float2*)(ws + 54542336);     // 4096*64*8   = 2097152
  float*  pos    = (float*)(ws + 56639488);      // 4096*4      = 16384
  float*  lse    = (float*)(ws + 56655872);      // 4096*4      = 16384
  // total = 56672256 bytes (~54 MB)

  k_norm<<<9216, 256, 0, stream>>>(zi, zj, queue, featb, queueb);
  k_argmax_gemm<<<8192, 256, 0, stream>>>(featb, queueb, part);
  k_argmax_reduce<<<1024, 256, 0, stream>>>(part, nnidx);
  k_sim_gemm<<<1024, 256, 0, stream>>>(featb, queueb, nnidx, lsep, pos);
  k_lse<<<1024, 256, 0, stream>>>(lsep, lse);
  k_final<<<1, 256, 0, stream>>>(lse, pos, out);
}

// Round 2
// 279.859 us; speedup vs baseline: 1.2159x; 1.2159x over previous
//
#include <hip/hip_runtime.h>
#include <cstdint>

#define NFEAT 4096
#define NHALF 2048
#define DDIM  512
#define QROWS 32768

typedef unsigned short u16;
typedef unsigned int   u32;
typedef unsigned long long u64;

typedef __bf16 bf16x8_t __attribute__((ext_vector_type(8)));
typedef float  f32x4_t  __attribute__((ext_vector_type(4)));

typedef const __attribute__((address_space(1))) void* gas_ptr;
typedef __attribute__((address_space(3))) void* las_ptr;

__device__ __forceinline__ u16 f2bf(float f) {
  u32 u = __float_as_uint(f);
  u32 r = u + 0x7FFFu + ((u >> 16) & 1u);
  return (u16)(r >> 16);
}

// monotonic unsigned encoding of float (no NaN/Inf expected)
__device__ __forceinline__ u32 fkey(float f) {
  u32 u = __float_as_uint(f);
  return (u & 0x80000000u) ? ~u : (u | 0x80000000u);
}

__device__ __forceinline__ void wait_vm0_barrier() {
  asm volatile("s_waitcnt vmcnt(0)" ::: "memory");
  __builtin_amdgcn_s_barrier();
  __builtin_amdgcn_sched_barrier(0);
}

// ---------------- kernel 1: l2-normalize rows -> bf16 ----------------
__global__ void k_norm(const float* __restrict__ zi, const float* __restrict__ zj,
                       const float* __restrict__ queue,
                       u16* __restrict__ featb, u16* __restrict__ queueb) {
  int gw = (int)((blockIdx.x * blockDim.x + threadIdx.x) >> 6);
  int lane = threadIdx.x & 63;
  const float* src; u16* dst;
  if (gw < NFEAT) {
    src = (gw < NHALF) ? (zi + (size_t)gw * DDIM) : (zj + (size_t)(gw - NHALF) * DDIM);
    dst = featb + (size_t)gw * DDIM;
  } else {
    int r = gw - NFEAT;
    src = queue + (size_t)r * DDIM;
    dst = queueb + (size_t)r * DDIM;
  }
  float4 v0 = reinterpret_cast<const float4*>(src)[lane * 2];
  float4 v1 = reinterpret_cast<const float4*>(src)[lane * 2 + 1];
  float ss = v0.x*v0.x + v0.y*v0.y + v0.z*v0.z + v0.w*v0.w
           + v1.x*v1.x + v1.y*v1.y + v1.z*v1.z + v1.w*v1.w;
  #pragma unroll
  for (int off = 32; off >= 1; off >>= 1) ss += __shfl_xor(ss, off);
  float inv = 1.0f / fmaxf(sqrtf(ss), 1e-12f);
  ushort4 o0, o1;
  o0.x = f2bf(v0.x * inv); o0.y = f2bf(v0.y * inv);
  o0.z = f2bf(v0.z * inv); o0.w = f2bf(v0.w * inv);
  o1.x = f2bf(v1.x * inv); o1.y = f2bf(v1.y * inv);
  o1.z = f2bf(v1.z * inv); o1.w = f2bf(v1.w * inv);
  reinterpret_cast<ushort4*>(dst)[lane * 2]     = o0;
  reinterpret_cast<ushort4*>(dst)[lane * 2 + 1] = o1;
}

// ---------------- GEMM common geometry ----------------
// BM=BN=128, BK=64, 256 threads = 4 waves (2x2), each wave 64x64 out (4x4 frags of 16x16)
// Double-buffered LDS (64 KB); XOR-swizzled layout: LDS element (row, e) holds
// global col e ^ ((row&7)<<3). Staged via pre-swizzled global source (rule #21).
#define BM 128
#define BN 128
#define BK 64

// ---------------- kernel 2: features @ queue^T with fused row-argmax ----------------
__global__ __launch_bounds__(256) void k_argmax_gemm(
    const u16* __restrict__ featb, const u16* __restrict__ queueb,
    u64* __restrict__ part) {
  __shared__ u16 As[2][BM * BK];
  __shared__ u16 Bs[2][BN * BK];
  const int tid = threadIdx.x;
  const int w = tid >> 6, lane = tid & 63;
  const int wr = w >> 1, wc = w & 1;
  // bijective XCD swizzle: 8192 blocks = 8 XCDs x 1024; each XCD gets a contiguous qt range
  const int bid = (int)blockIdx.x;
  const int wg = (bid & 7) * 1024 + (bid >> 3);
  const int mt = wg & 31;
  const int qt = wg >> 5;
  const int brow = mt * BM, bcol = qt * BN;
  const int srow = lane >> 3;
  const int scol = ((lane & 7) ^ srow) * 8;      // pre-swizzled source column
  const int lg = lane >> 4, li = lane & 15;
  const int sw = (li & 7) << 3;                  // read-side swizzle

  const u16* gA = featb  + (size_t)(brow + srow) * DDIM + scol;
  const u16* gB = queueb + (size_t)(bcol + srow) * DDIM + scol;

  f32x4_t acc[4][4] = {};

  auto stage = [&](int b, int kt) {
    #pragma unroll
    for (int i = 0; i < 4; i++) {
      const int r0 = (w * 4 + i) * 8;
      __builtin_amdgcn_global_load_lds((gas_ptr)(gA + (size_t)r0 * DDIM + kt),
                                       (las_ptr)&As[b][r0 * BK], 16, 0, 0);
      __builtin_amdgcn_global_load_lds((gas_ptr)(gB + (size_t)r0 * DDIM + kt),
                                       (las_ptr)&Bs[b][r0 * BK], 16, 0, 0);
    }
  };
  auto compute = [&](int b) {
    #pragma unroll
    for (int kk = 0; kk < 2; kk++) {
      bf16x8_t af[4], bfr[4];
      const int ko = kk * 32 + lg * 8;
      #pragma unroll
      for (int m = 0; m < 4; m++)
        af[m] = *reinterpret_cast<const bf16x8_t*>(&As[b][(wr*64 + m*16 + li) * BK + (ko ^ sw)]);
      #pragma unroll
      for (int n = 0; n < 4; n++)
        bfr[n] = *reinterpret_cast<const bf16x8_t*>(&Bs[b][(wc*64 + n*16 + li) * BK + (ko ^ sw)]);
      __builtin_amdgcn_s_setprio(1);
      #pragma unroll
      for (int m = 0; m < 4; m++)
        #pragma unroll
        for (int n = 0; n < 4; n++)
          acc[m][n] = __builtin_amdgcn_mfma_f32_16x16x32_bf16(af[m], bfr[n], acc[m][n], 0, 0, 0);
      __builtin_amdgcn_s_setprio(0);
    }
  };

  // prologue
  stage(0, 0);
  wait_vm0_barrier();
  // pipelined main loop: 8 K-steps total
  #pragma unroll
  for (int tt = 0; tt < 7; tt++) {
    stage((tt + 1) & 1, (tt + 1) * BK);   // issue next-tile loads (stay in flight)
    compute(tt & 1);                       // ds_read + MFMA current tile
    wait_vm0_barrier();                    // one drain+barrier per K-step
  }
  compute(1);

  // epilogue: per-row argmax over this block's 128 cols
  #pragma unroll
  for (int m = 0; m < 4; m++) {
    #pragma unroll
    for (int j = 0; j < 4; j++) {
      u64 best = 0;
      #pragma unroll
      for (int n = 0; n < 4; n++) {
        float v = acc[m][n][j];
        u32 col = (u32)(bcol + wc*64 + n*16 + li);
        u64 key = ((u64)fkey(v) << 32) | (u64)(0xFFFFFFFFu - col);
        best = best > key ? best : key;
      }
      #pragma unroll
      for (int off = 1; off < 16; off <<= 1) {
        u64 o = __shfl_xor(best, off);
        best = best > o ? best : o;
      }
      if (li == 0) {
        int row = brow + wr*64 + m*16 + lg*4 + j;
        part[(size_t)row * 512 + (qt*2 + wc)] = best;
      }
    }
  }
}

// ---------------- kernel 3: reduce argmax partials -> nn_idx ----------------
__global__ void k_argmax_reduce(const u64* __restrict__ part, int* __restrict__ nnidx) {
  int row = (int)((blockIdx.x * blockDim.x + threadIdx.x) >> 6);
  int lane = threadIdx.x & 63;
  const u64* p = part + (size_t)row * 512;
  u64 best = 0;
  #pragma unroll
  for (int i = 0; i < 8; i++) { u64 v = p[lane * 8 + i]; best = best > v ? best : v; }
  #pragma unroll
  for (int off = 1; off < 64; off <<= 1) { u64 o = __shfl_xor(best, off); best = best > o ? best : o; }
  if (lane == 0) nnidx[row] = (int)(0xFFFFFFFFu - (u32)(best & 0xFFFFFFFFu));
}

// ---------------- kernel 4: sim = nn_feats @ features^T / T, fused lse partials + positives ----
__global__ __launch_bounds__(256) void k_sim_gemm(
    const u16* __restrict__ featb, const u16* __restrict__ queueb,
    const int* __restrict__ nnidx,
    float2* __restrict__ lsep, float* __restrict__ pos) {
  __shared__ u16 As[2][BM * BK];
  __shared__ u16 Bs[2][BN * BK];
  const int tid = threadIdx.x;
  const int w = tid >> 6, lane = tid & 63;
  const int wr = w >> 1, wc = w & 1;
  // XCD swizzle: 1024 blocks = 8 x 128
  const int bid = (int)blockIdx.x;
  const int wg = (bid & 7) * 128 + (bid >> 3);
  const int mt = wg & 31;
  const int ct = wg >> 5;
  const int brow = mt * BM, bcol = ct * BN;
  const int srow = lane >> 3;
  const int scol = ((lane & 7) ^ srow) * 8;
  const int lg = lane >> 4, li = lane & 15;
  const int sw = (li & 7) << 3;

  int ridx[4];
  #pragma unroll
  for (int i = 0; i < 4; i++) ridx[i] = nnidx[brow + (w*4 + i)*8 + srow];

  const u16* gB = featb + (size_t)(bcol + srow) * DDIM + scol;

  f32x4_t acc[4][4] = {};

  auto stage = [&](int b, int kt) {
    #pragma unroll
    for (int i = 0; i < 4; i++) {
      const int r0 = (w * 4 + i) * 8;
      __builtin_amdgcn_global_load_lds((gas_ptr)(queueb + (size_t)ridx[i] * DDIM + kt + scol),
                                       (las_ptr)&As[b][r0 * BK], 16, 0, 0);
      __builtin_amdgcn_global_load_lds((gas_ptr)(gB + (size_t)r0 * DDIM + kt),
                                       (las_ptr)&Bs[b][r0 * BK], 16, 0, 0);
    }
  };
  auto compute = [&](int b) {
    #pragma unroll
    for (int kk = 0; kk < 2; kk++) {
      bf16x8_t af[4], bfr[4];
      const int ko = kk * 32 + lg * 8;
      #pragma unroll
      for (int m = 0; m < 4; m++)
        af[m] = *reinterpret_cast<const bf16x8_t*>(&As[b][(wr*64 + m*16 + li) * BK + (ko ^ sw)]);
      #pragma unroll
      for (int n = 0; n < 4; n++)
        bfr[n] = *reinterpret_cast<const bf16x8_t*>(&Bs[b][(wc*64 + n*16 + li) * BK + (ko ^ sw)]);
      __builtin_amdgcn_s_setprio(1);
      #pragma unroll
      for (int m = 0; m < 4; m++)
        #pragma unroll
        for (int n = 0; n < 4; n++)
          acc[m][n] = __builtin_amdgcn_mfma_f32_16x16x32_bf16(af[m], bfr[n], acc[m][n], 0, 0, 0);
      __builtin_amdgcn_s_setprio(0);
    }
  };

  stage(0, 0);
  wait_vm0_barrier();
  #pragma unroll
  for (int tt = 0; tt < 7; tt++) {
    stage((tt + 1) & 1, (tt + 1) * BK);
    compute(tt & 1);
    wait_vm0_barrier();
  }
  compute(1);

  // epilogue: scale by 1/T=2, capture positives, mask diag, per-row (max, sumexp) over 128 cols
  #pragma unroll
  for (int m = 0; m < 4; m++) {
    #pragma unroll
    for (int j = 0; j < 4; j++) {
      int row = brow + wr*64 + m*16 + lg*4 + j;
      float vals[4];
      float vmax = -3.0e38f;
      #pragma unroll
      for (int n = 0; n < 4; n++) {
        int col = bcol + wc*64 + n*16 + li;
        float v = acc[m][n][j] * 2.0f;
        if (col == (row ^ NHALF)) pos[row] = v;   // positive sample (unique writer)
        if (col == row) v = -1.0e30f;             // diag mask
        vals[n] = v;
        vmax = fmaxf(vmax, v);
      }
      float s = 0.f;
      #pragma unroll
      for (int n = 0; n < 4; n++) s += __expf(vals[n] - vmax);
      #pragma unroll
      for (int off = 1; off < 16; off <<= 1) {
        float mo = __shfl_xor(vmax, off);
        float so = __shfl_xor(s, off);
        float M = fmaxf(vmax, mo);
        s = s * __expf(vmax - M) + so * __expf(mo - M);
        vmax = M;
      }
      if (li == 0) lsep[(size_t)row * 64 + (ct*2 + wc)] = make_float2(vmax, s);
    }
  }
}

// ---------------- kernel 5: per-row logsumexp merge ----------------
__global__ void k_lse(const float2* __restrict__ lsep, float* __restrict__ lse) {
  int row = (int)((blockIdx.x * blockDim.x + threadIdx.x) >> 6);
  int lane = threadIdx.x & 63;
  float2 p = lsep[(size_t)row * 64 + lane];
  float m = p.x, s = p.y;
  #pragma unroll
  for (int off = 1; off < 64; off <<= 1) {
    float mo = __shfl_xor(m, off), so = __shfl_xor(s, off);
    float M = fmaxf(m, mo);
    s = s * __expf(m - M) + so * __expf(mo - M);
    m = M;
  }
  if (lane == 0) lse[row] = m + __logf(s);
}

// ---------------- kernel 6: final scalar ----------------
__global__ void k_final(const float* __restrict__ lse, const float* __restrict__ pos,
                        float* __restrict__ out) {
  __shared__ float red[4];
  int tid = threadIdx.x;
  float a = 0.f;
  for (int i = tid; i < NFEAT; i += 256) a += lse[i] - pos[i];
  #pragma unroll
  for (int off = 32; off >= 1; off >>= 1) a += __shfl_xor(a, off);
  if ((tid & 63) == 0) red[tid >> 6] = a;
  __syncthreads();
  if (tid == 0) out[0] = (red[0] + red[1] + red[2] + red[3]) / (float)NFEAT;
}

extern "C" void kernel_launch(void* const* d_in, const int* in_sizes, int n_in,
                              void* d_out, int out_size, void* d_ws, size_t ws_size,
                              hipStream_t stream) {
  const float* zi    = (const float*)d_in[0];
  const float* zj    = (const float*)d_in[1];
  const float* queue = (const float*)d_in[2];
  float* out = (float*)d_out;
  char* ws = (char*)d_ws;

  // ws layout (bytes):
  u16*    queueb = (u16*)(ws + 0);               // 32768*512*2 = 33554432
  u16*    featb  = (u16*)(ws + 33554432);        // 4096*512*2  = 4194304
  u64*    part   = (u64*)(ws + 37748736);        // 4096*512*8  = 16777216
  int*    nnidx  = (int*)(ws + 54525952);        // 4096*4      = 16384
  float2* lsep   = (float2*)(ws + 54542336);     // 4096*64*8   = 2097152
  float*  pos    = (float*)(ws + 56639488);      // 4096*4      = 16384
  float*  lse    = (float*)(ws + 56655872);      // 4096*4      = 16384
  // total = 56672256 bytes (~54 MB)

  k_norm<<<9216, 256, 0, stream>>>(zi, zj, queue, featb, queueb);
  k_argmax_gemm<<<8192, 256, 0, stream>>>(featb, queueb, part);
  k_argmax_reduce<<<1024, 256, 0, stream>>>(part, nnidx);
  k_sim_gemm<<<1024, 256, 0, stream>>>(featb, queueb, nnidx, lsep, pos);
  k_lse<<<1024, 256, 0, stream>>>(lsep, lse);
  k_final<<<1, 256, 0, stream>>>(lse, pos, out);
}

// Round 3
// 268.959 us; speedup vs baseline: 1.2652x; 1.0405x over previous
//
#include <hip/hip_runtime.h>
#include <cstdint>

#define NFEAT 4096
#define NHALF 2048
#define DDIM  512
#define QROWS 32768

typedef unsigned short u16;
typedef unsigned int   u32;
typedef unsigned long long u64;

typedef __bf16 bf16x8_t __attribute__((ext_vector_type(8)));
typedef float  f32x4_t  __attribute__((ext_vector_type(4)));

typedef const __attribute__((address_space(1))) void* gas_ptr;
typedef __attribute__((address_space(3))) void* las_ptr;

#define BAR() do { __builtin_amdgcn_s_barrier(); __builtin_amdgcn_sched_barrier(0); } while (0)

__device__ __forceinline__ u16 f2bf(float f) {
  u32 u = __float_as_uint(f);
  u32 r = u + 0x7FFFu + ((u >> 16) & 1u);
  return (u16)(r >> 16);
}

// monotonic unsigned encoding of float (no NaN/Inf expected)
__device__ __forceinline__ u32 fkey(float f) {
  u32 u = __float_as_uint(f);
  return (u & 0x80000000u) ? ~u : (u | 0x80000000u);
}

// ---------------- kernel 1: l2-normalize rows -> bf16 ----------------
__global__ void k_norm(const float* __restrict__ zi, const float* __restrict__ zj,
                       const float* __restrict__ queue,
                       u16* __restrict__ featb, u16* __restrict__ queueb) {
  int gw = (int)((blockIdx.x * blockDim.x + threadIdx.x) >> 6);
  int lane = threadIdx.x & 63;
  const float* src; u16* dst;
  if (gw < NFEAT) {
    src = (gw < NHALF) ? (zi + (size_t)gw * DDIM) : (zj + (size_t)(gw - NHALF) * DDIM);
    dst = featb + (size_t)gw * DDIM;
  } else {
    int r = gw - NFEAT;
    src = queue + (size_t)r * DDIM;
    dst = queueb + (size_t)r * DDIM;
  }
  float4 v0 = reinterpret_cast<const float4*>(src)[lane * 2];
  float4 v1 = reinterpret_cast<const float4*>(src)[lane * 2 + 1];
  float ss = v0.x*v0.x + v0.y*v0.y + v0.z*v0.z + v0.w*v0.w
           + v1.x*v1.x + v1.y*v1.y + v1.z*v1.z + v1.w*v1.w;
  #pragma unroll
  for (int off = 32; off >= 1; off >>= 1) ss += __shfl_xor(ss, off);
  float inv = 1.0f / fmaxf(sqrtf(ss), 1e-12f);
  ushort4 o0, o1;
  o0.x = f2bf(v0.x * inv); o0.y = f2bf(v0.y * inv);
  o0.z = f2bf(v0.z * inv); o0.w = f2bf(v0.w * inv);
  o1.x = f2bf(v1.x * inv); o1.y = f2bf(v1.y * inv);
  o1.z = f2bf(v1.z * inv); o1.w = f2bf(v1.w * inv);
  reinterpret_cast<ushort4*>(dst)[lane * 2]     = o0;
  reinterpret_cast<ushort4*>(dst)[lane * 2 + 1] = o1;
}

// ---------------- GEMM geometry ----------------
// BM=BN=256, BK=32, 512 threads = 8 waves (2 x 4). Wave tile 128x64 (8x4 frags).
// LDS: 4-deep K-tile ring, each tile = A[256x32] + B[256x32] bf16 = 32 KB -> 128 KB.
// Layout per tile: half0 = rows 0..127 (4096 elems), half1 = rows 128..255.
// Swizzle: LDS slot (r,u) [u = 16B slot 0..3] holds global K-slot s=(u-((r>>1)&3))&3.
// Staged via linear global_load_lds dest + pre-permuted global source (rule #21).
// Pipeline: while computing tile t, stage tile t+3 into buf[(t+3)&3] (== buf[(t-1)&3],
// whose reads finished before t's first barrier). Boundary s_waitcnt vmcnt(8):
// outstanding = stages of t+2,t+3 (4 instr each); forces t+1's stages landed.

// ---------------- kernel 2: features @ queue^T with fused row-argmax ----------------
__global__ __launch_bounds__(512, 2) void k_argmax_gemm(
    const u16* __restrict__ featb, const u16* __restrict__ queueb,
    u64* __restrict__ part) {
  __shared__ u16 As[4][8192];
  __shared__ u16 Bs[4][8192];
  const int tid = threadIdx.x;
  const int w = tid >> 6, lane = tid & 63;
  const int wr = w >> 2, wc = w & 3;
  const int li = lane & 15, lg = lane >> 4;
  // bijective XCD swizzle: 2048 blocks = 8 XCDs x 256
  const int bid = (int)blockIdx.x;
  const int wg = (bid & 7) * 256 + (bid >> 3);
  const int mt = wg & 15, qt = wg >> 4;
  const int brow = mt * 256, bcol = qt * 256;

  // write-side: thread stages 16B at LDS elem tid*8 of each half; source K-slot permuted
  const int sr = tid >> 2;                              // row within half
  const int s  = ((tid & 3) - ((tid >> 3) & 3)) & 3;    // global K-slot for this thread
  const u16* gA0 = featb  + (size_t)(brow + sr) * DDIM + s * 8;
  const u16* gA1 = featb  + (size_t)(brow + 128 + sr) * DDIM + s * 8;
  const u16* gB0 = queueb + (size_t)(bcol + sr) * DDIM + s * 8;
  const u16* gB1 = queueb + (size_t)(bcol + 128 + sr) * DDIM + s * 8;
  const int wofs = w * 512;                             // wave's elem base within half

  // read-side frag elem offsets (slot = inverse swizzle, 2-way bank aliasing = free)
  const int slot = ((lg + ((li >> 1) & 3)) & 3) * 8;
  int aoff[8], boff[4];
  #pragma unroll
  for (int m = 0; m < 8; m++) aoff[m] = wr * 4096 + (m * 16 + li) * 32 + slot;
  #pragma unroll
  for (int n = 0; n < 4; n++) boff[n] = (wc >> 1) * 4096 + ((wc & 1) * 64 + n * 16 + li) * 32 + slot;

  f32x4_t acc[8][4] = {};

  auto stA = [&](int buf, int t) {
    __builtin_amdgcn_global_load_lds((gas_ptr)(gA0 + t * 32), (las_ptr)&As[buf][wofs], 16, 0, 0);
    __builtin_amdgcn_global_load_lds((gas_ptr)(gA1 + t * 32), (las_ptr)&As[buf][4096 + wofs], 16, 0, 0);
  };
  auto stB = [&](int buf, int t) {
    __builtin_amdgcn_global_load_lds((gas_ptr)(gB0 + t * 32), (las_ptr)&Bs[buf][wofs], 16, 0, 0);
    __builtin_amdgcn_global_load_lds((gas_ptr)(gB1 + t * 32), (las_ptr)&Bs[buf][4096 + wofs], 16, 0, 0);
  };

  // prologue: stage tiles 0,1,2; wait until tile 0 landed (newest 8 = tiles 1,2)
  stA(0, 0); stB(0, 0); stA(1, 1); stB(1, 1); stA(2, 2); stB(2, 2);
  asm volatile("s_waitcnt vmcnt(8)" ::: "memory");
  BAR();

  #pragma unroll
  for (int t = 0; t < 16; t++) {
    const int rb = t & 3;
    // ---- phase 1: quadrant m=0..3 ----
    bf16x8_t bfr[4], af[4];
    #pragma unroll
    for (int n = 0; n < 4; n++) bfr[n] = *reinterpret_cast<const bf16x8_t*>(&Bs[rb][boff[n]]);
    #pragma unroll
    for (int m = 0; m < 4; m++) af[m] = *reinterpret_cast<const bf16x8_t*>(&As[rb][aoff[m]]);
    if (t < 13) stA((t + 3) & 3, t + 3);
    BAR();
    __builtin_amdgcn_s_setprio(1);
    #pragma unroll
    for (int m = 0; m < 4; m++)
      #pragma unroll
      for (int n = 0; n < 4; n++)
        acc[m][n] = __builtin_amdgcn_mfma_f32_16x16x32_bf16(af[m], bfr[n], acc[m][n], 0, 0, 0);
    __builtin_amdgcn_s_setprio(0);
    BAR();
    // ---- phase 2: quadrant m=4..7 + K-tile boundary ----
    bf16x8_t af2[4];
    #pragma unroll
    for (int m = 0; m < 4; m++) af2[m] = *reinterpret_cast<const bf16x8_t*>(&As[rb][aoff[4 + m]]);
    if (t < 13) stB((t + 3) & 3, t + 3);
    asm volatile("s_waitcnt lgkmcnt(0)" ::: "memory");   // all reads of tile t done pre-barrier
    __builtin_amdgcn_sched_barrier(0);
    if (t <= 12)      { asm volatile("s_waitcnt vmcnt(8)" ::: "memory"); }
    else if (t == 13) { asm volatile("s_waitcnt vmcnt(4)" ::: "memory"); }
    else if (t == 14) { asm volatile("s_waitcnt vmcnt(0)" ::: "memory"); }
    BAR();
    __builtin_amdgcn_s_setprio(1);
    #pragma unroll
    for (int m = 0; m < 4; m++)
      #pragma unroll
      for (int n = 0; n < 4; n++)
        acc[4 + m][n] = __builtin_amdgcn_mfma_f32_16x16x32_bf16(af2[m], bfr[n], acc[4 + m][n], 0, 0, 0);
    __builtin_amdgcn_s_setprio(0);
    BAR();
  }

  // epilogue: per-row argmax over this block's 256 cols (wave owns 64 cols)
  #pragma unroll
  for (int m = 0; m < 8; m++) {
    #pragma unroll
    for (int j = 0; j < 4; j++) {
      u64 best = 0;
      #pragma unroll
      for (int n = 0; n < 4; n++) {
        float v = acc[m][n][j];
        u32 col = (u32)(bcol + wc * 64 + n * 16 + li);
        u64 key = ((u64)fkey(v) << 32) | (u64)(0xFFFFFFFFu - col);
        best = best > key ? best : key;
      }
      #pragma unroll
      for (int off = 1; off < 16; off <<= 1) {
        u64 o = __shfl_xor(best, off);
        best = best > o ? best : o;
      }
      if (li == 0) {
        int row = brow + wr * 128 + m * 16 + lg * 4 + j;
        part[(size_t)row * 512 + (qt * 4 + wc)] = best;
      }
    }
  }
}

// ---------------- kernel 3: reduce argmax partials -> nn_idx ----------------
__global__ void k_argmax_reduce(const u64* __restrict__ part, int* __restrict__ nnidx) {
  int row = (int)((blockIdx.x * blockDim.x + threadIdx.x) >> 6);
  int lane = threadIdx.x & 63;
  const u64* p = part + (size_t)row * 512;
  u64 best = 0;
  #pragma unroll
  for (int i = 0; i < 8; i++) { u64 v = p[lane * 8 + i]; best = best > v ? best : v; }
  #pragma unroll
  for (int off = 1; off < 64; off <<= 1) { u64 o = __shfl_xor(best, off); best = best > o ? best : o; }
  if (lane == 0) nnidx[row] = (int)(0xFFFFFFFFu - (u32)(best & 0xFFFFFFFFu));
}

// ---------------- kernel 4: sim = nn_feats @ features^T / T, fused lse + positives ----
__global__ __launch_bounds__(512, 2) void k_sim_gemm(
    const u16* __restrict__ featb, const u16* __restrict__ queueb,
    const int* __restrict__ nnidx,
    float2* __restrict__ lsep, float* __restrict__ pos) {
  __shared__ u16 As[4][8192];
  __shared__ u16 Bs[4][8192];
  const int tid = threadIdx.x;
  const int w = tid >> 6, lane = tid & 63;
  const int wr = w >> 2, wc = w & 3;
  const int li = lane & 15, lg = lane >> 4;
  // XCD swizzle: 256 blocks = 8 x 32
  const int bid = (int)blockIdx.x;
  const int wg = (bid & 7) * 32 + (bid >> 3);
  const int mt = wg & 15, ct = wg >> 4;
  const int brow = mt * 256, bcol = ct * 256;

  const int sr = tid >> 2;
  const int s  = ((tid & 3) - ((tid >> 3) & 3)) & 3;
  const int r0i = nnidx[brow + sr];
  const int r1i = nnidx[brow + 128 + sr];
  const u16* gA0 = queueb + (size_t)r0i * DDIM + s * 8;   // gathered NN rows
  const u16* gA1 = queueb + (size_t)r1i * DDIM + s * 8;
  const u16* gB0 = featb  + (size_t)(bcol + sr) * DDIM + s * 8;
  const u16* gB1 = featb  + (size_t)(bcol + 128 + sr) * DDIM + s * 8;
  const int wofs = w * 512;

  const int slot = ((lg + ((li >> 1) & 3)) & 3) * 8;
  int aoff[8], boff[4];
  #pragma unroll
  for (int m = 0; m < 8; m++) aoff[m] = wr * 4096 + (m * 16 + li) * 32 + slot;
  #pragma unroll
  for (int n = 0; n < 4; n++) boff[n] = (wc >> 1) * 4096 + ((wc & 1) * 64 + n * 16 + li) * 32 + slot;

  f32x4_t acc[8][4] = {};

  auto stA = [&](int buf, int t) {
    __builtin_amdgcn_global_load_lds((gas_ptr)(gA0 + t * 32), (las_ptr)&As[buf][wofs], 16, 0, 0);
    __builtin_amdgcn_global_load_lds((gas_ptr)(gA1 + t * 32), (las_ptr)&As[buf][4096 + wofs], 16, 0, 0);
  };
  auto stB = [&](int buf, int t) {
    __builtin_amdgcn_global_load_lds((gas_ptr)(gB0 + t * 32), (las_ptr)&Bs[buf][wofs], 16, 0, 0);
    __builtin_amdgcn_global_load_lds((gas_ptr)(gB1 + t * 32), (las_ptr)&Bs[buf][4096 + wofs], 16, 0, 0);
  };

  stA(0, 0); stB(0, 0); stA(1, 1); stB(1, 1); stA(2, 2); stB(2, 2);
  asm volatile("s_waitcnt vmcnt(8)" ::: "memory");
  BAR();

  #pragma unroll
  for (int t = 0; t < 16; t++) {
    const int rb = t & 3;
    bf16x8_t bfr[4], af[4];
    #pragma unroll
    for (int n = 0; n < 4; n++) bfr[n] = *reinterpret_cast<const bf16x8_t*>(&Bs[rb][boff[n]]);
    #pragma unroll
    for (int m = 0; m < 4; m++) af[m] = *reinterpret_cast<const bf16x8_t*>(&As[rb][aoff[m]]);
    if (t < 13) stA((t + 3) & 3, t + 3);
    BAR();
    __builtin_amdgcn_s_setprio(1);
    #pragma unroll
    for (int m = 0; m < 4; m++)
      #pragma unroll
      for (int n = 0; n < 4; n++)
        acc[m][n] = __builtin_amdgcn_mfma_f32_16x16x32_bf16(af[m], bfr[n], acc[m][n], 0, 0, 0);
    __builtin_amdgcn_s_setprio(0);
    BAR();
    bf16x8_t af2[4];
    #pragma unroll
    for (int m = 0; m < 4; m++) af2[m] = *reinterpret_cast<const bf16x8_t*>(&As[rb][aoff[4 + m]]);
    if (t < 13) stB((t + 3) & 3, t + 3);
    asm volatile("s_waitcnt lgkmcnt(0)" ::: "memory");
    __builtin_amdgcn_sched_barrier(0);
    if (t <= 12)      { asm volatile("s_waitcnt vmcnt(8)" ::: "memory"); }
    else if (t == 13) { asm volatile("s_waitcnt vmcnt(4)" ::: "memory"); }
    else if (t == 14) { asm volatile("s_waitcnt vmcnt(0)" ::: "memory"); }
    BAR();
    __builtin_amdgcn_s_setprio(1);
    #pragma unroll
    for (int m = 0; m < 4; m++)
      #pragma unroll
      for (int n = 0; n < 4; n++)
        acc[4 + m][n] = __builtin_amdgcn_mfma_f32_16x16x32_bf16(af2[m], bfr[n], acc[4 + m][n], 0, 0, 0);
    __builtin_amdgcn_s_setprio(0);
    BAR();
  }

  // epilogue: scale by 1/T=2, positives, diag mask, per-row (max, sumexp) over 64 cols
  #pragma unroll
  for (int m = 0; m < 8; m++) {
    #pragma unroll
    for (int j = 0; j < 4; j++) {
      int row = brow + wr * 128 + m * 16 + lg * 4 + j;
      float vals[4];
      float vmax = -3.0e38f;
      #pragma unroll
      for (int n = 0; n < 4; n++) {
        int col = bcol + wc * 64 + n * 16 + li;
        float v = acc[m][n][j] * 2.0f;
        if (col == (row ^ NHALF)) pos[row] = v;   // positive sample (unique writer)
        if (col == row) v = -1.0e30f;             // diag mask
        vals[n] = v;
        vmax = fmaxf(vmax, v);
      }
      float sum = 0.f;
      #pragma unroll
      for (int n = 0; n < 4; n++) sum += __expf(vals[n] - vmax);
      #pragma unroll
      for (int off = 1; off < 16; off <<= 1) {
        float mo = __shfl_xor(vmax, off);
        float so = __shfl_xor(sum, off);
        float M = fmaxf(vmax, mo);
        sum = sum * __expf(vmax - M) + so * __expf(mo - M);
        vmax = M;
      }
      if (li == 0) lsep[(size_t)row * 64 + (ct * 4 + wc)] = make_float2(vmax, sum);
    }
  }
}

// ---------------- kernel 5: per-row logsumexp merge ----------------
__global__ void k_lse(const float2* __restrict__ lsep, float* __restrict__ lse) {
  int row = (int)((blockIdx.x * blockDim.x + threadIdx.x) >> 6);
  int lane = threadIdx.x & 63;
  float2 p = lsep[(size_t)row * 64 + lane];
  float m = p.x, s = p.y;
  #pragma unroll
  for (int off = 1; off < 64; off <<= 1) {
    float mo = __shfl_xor(m, off), so = __shfl_xor(s, off);
    float M = fmaxf(m, mo);
    s = s * __expf(m - M) + so * __expf(mo - M);
    m = M;
  }
  if (lane == 0) lse[row] = m + __logf(s);
}

// ---------------- kernel 6: final scalar ----------------
__global__ void k_final(const float* __restrict__ lse, const float* __restrict__ pos,
                        float* __restrict__ out) {
  __shared__ float red[4];
  int tid = threadIdx.x;
  float a = 0.f;
  for (int i = tid; i < NFEAT; i += 256) a += lse[i] - pos[i];
  #pragma unroll
  for (int off = 32; off >= 1; off >>= 1) a += __shfl_xor(a, off);
  if ((tid & 63) == 0) red[tid >> 6] = a;
  __syncthreads();
  if (tid == 0) out[0] = (red[0] + red[1] + red[2] + red[3]) / (float)NFEAT;
}

extern "C" void kernel_launch(void* const* d_in, const int* in_sizes, int n_in,
                              void* d_out, int out_size, void* d_ws, size_t ws_size,
                              hipStream_t stream) {
  const float* zi    = (const float*)d_in[0];
  const float* zj    = (const float*)d_in[1];
  const float* queue = (const float*)d_in[2];
  float* out = (float*)d_out;
  char* ws = (char*)d_ws;

  // ws layout (bytes):
  u16*    queueb = (u16*)(ws + 0);               // 32768*512*2 = 33554432
  u16*    featb  = (u16*)(ws + 33554432);        // 4096*512*2  = 4194304
  u64*    part   = (u64*)(ws + 37748736);        // 4096*512*8  = 16777216
  int*    nnidx  = (int*)(ws + 54525952);        // 4096*4      = 16384
  float2* lsep   = (float2*)(ws + 54542336);     // 4096*64*8   = 2097152
  float*  pos    = (float*)(ws + 56639488);      // 4096*4      = 16384
  float*  lse    = (float*)(ws + 56655872);      // 4096*4      = 16384
  // total = 56672256 bytes (~54 MB)

  k_norm<<<9216, 256, 0, stream>>>(zi, zj, queue, featb, queueb);
  k_argmax_gemm<<<2048, 512, 0, stream>>>(featb, queueb, part);
  k_argmax_reduce<<<1024, 256, 0, stream>>>(part, nnidx);
  k_sim_gemm<<<256, 512, 0, stream>>>(featb, queueb, nnidx, lsep, pos);
  k_lse<<<1024, 256, 0, stream>>>(lsep, lse);
  k_final<<<1, 256, 0, stream>>>(lse, pos, out);
}

// Round 4
// 267.225 us; speedup vs baseline: 1.2734x; 1.0065x over previous
//
#include <hip/hip_runtime.h>
#include <cstdint>

#define NFEAT 4096
#define NHALF 2048
#define DDIM  512
#define QROWS 32768

typedef unsigned short u16;
typedef unsigned int   u32;
typedef unsigned long long u64;

typedef __bf16 bf16x8_t __attribute__((ext_vector_type(8)));
typedef float  f32x4_t  __attribute__((ext_vector_type(4)));

typedef const __attribute__((address_space(1))) void* gas_ptr;
typedef __attribute__((address_space(3))) void* las_ptr;

__device__ __forceinline__ u16 f2bf(float f) {
  u32 u = __float_as_uint(f);
  u32 r = u + 0x7FFFu + ((u >> 16) & 1u);
  return (u16)(r >> 16);
}

// monotonic unsigned encoding of float (no NaN/Inf expected)
__device__ __forceinline__ u32 fkey(float f) {
  u32 u = __float_as_uint(f);
  return (u & 0x80000000u) ? ~u : (u | 0x80000000u);
}

// ---------------- kernel 1: l2-normalize rows -> bf16 ----------------
__global__ void k_norm(const float* __restrict__ zi, const float* __restrict__ zj,
                       const float* __restrict__ queue,
                       u16* __restrict__ featb, u16* __restrict__ queueb) {
  int gw = (int)((blockIdx.x * blockDim.x + threadIdx.x) >> 6);
  int lane = threadIdx.x & 63;
  const float* src; u16* dst;
  if (gw < NFEAT) {
    src = (gw < NHALF) ? (zi + (size_t)gw * DDIM) : (zj + (size_t)(gw - NHALF) * DDIM);
    dst = featb + (size_t)gw * DDIM;
  } else {
    int r = gw - NFEAT;
    src = queue + (size_t)r * DDIM;
    dst = queueb + (size_t)r * DDIM;
  }
  float4 v0 = reinterpret_cast<const float4*>(src)[lane * 2];
  float4 v1 = reinterpret_cast<const float4*>(src)[lane * 2 + 1];
  float ss = v0.x*v0.x + v0.y*v0.y + v0.z*v0.z + v0.w*v0.w
           + v1.x*v1.x + v1.y*v1.y + v1.z*v1.z + v1.w*v1.w;
  #pragma unroll
  for (int off = 32; off >= 1; off >>= 1) ss += __shfl_xor(ss, off);
  float inv = 1.0f / fmaxf(sqrtf(ss), 1e-12f);
  ushort4 o0, o1;
  o0.x = f2bf(v0.x * inv); o0.y = f2bf(v0.y * inv);
  o0.z = f2bf(v0.z * inv); o0.w = f2bf(v0.w * inv);
  o1.x = f2bf(v1.x * inv); o1.y = f2bf(v1.y * inv);
  o1.z = f2bf(v1.z * inv); o1.w = f2bf(v1.w * inv);
  reinterpret_cast<ushort4*>(dst)[lane * 2]     = o0;
  reinterpret_cast<ushort4*>(dst)[lane * 2 + 1] = o1;
}

// ---------------- GEMM geometry ----------------
// BM=BN=256, BK=32, 512 threads = 8 waves (2 x 4). Wave tile 128x64 (8x4 frags).
// LDS: 4-deep K-tile ring as EIGHT DISTINCT __shared__ arrays (A0..A3, B0..B3,
// 16 KB each = 128 KB) so the fully-unrolled t-loop gives the compiler exact
// alias info between ds_read(buf rb) and global_load_lds(buf (t+3)&3) -> no
// conservative vmcnt(0) drains before the fragment reads.
// Swizzle: LDS slot (r,u) [u = 16B slot 0..3] holds global K-slot s=(u-((r>>1)&3))&3.
// Staged via linear global_load_lds dest + pre-permuted global source.
// Pipeline: while computing tile t, stage tile t+3 into buf (t+3)&3 = (t-1)&3
// (all reads of t-1 consumed before t-1's final barrier; stage issued after ->
// WAR closed with no lgkmcnt needed). Boundary s_waitcnt vmcnt(8) per K-tile
// (never 0): forces tile t+1's 4 loads landed; barrier makes that global.

// ---------------- kernel 2: features @ queue^T with fused row-argmax ----------------
__global__ __launch_bounds__(512, 2) void k_argmax_gemm(
    const u16* __restrict__ featb, const u16* __restrict__ queueb,
    u64* __restrict__ part) {
  __shared__ u16 A0[8192], A1[8192], A2[8192], A3[8192];
  __shared__ u16 B0[8192], B1[8192], B2[8192], B3[8192];
  u16* const Ab[4] = {A0, A1, A2, A3};
  u16* const Bb[4] = {B0, B1, B2, B3};
  const int tid = threadIdx.x;
  const int w = tid >> 6, lane = tid & 63;
  const int wr = w >> 2, wc = w & 3;
  const int li = lane & 15, lg = lane >> 4;
  // bijective XCD swizzle: 2048 blocks = 8 XCDs x 256
  const int bid = (int)blockIdx.x;
  const int wg = (bid & 7) * 256 + (bid >> 3);
  const int mt = wg & 15, qt = wg >> 4;
  const int brow = mt * 256, bcol = qt * 256;

  // write-side: thread stages 16B at LDS elem tid*8 of each half; source K-slot permuted
  const int sr = tid >> 2;                              // row within half
  const int s  = ((tid & 3) - ((tid >> 3) & 3)) & 3;    // global K-slot for this thread
  const u16* gA0 = featb  + (size_t)(brow + sr) * DDIM + s * 8;
  const u16* gA1 = featb  + (size_t)(brow + 128 + sr) * DDIM + s * 8;
  const u16* gB0 = queueb + (size_t)(bcol + sr) * DDIM + s * 8;
  const u16* gB1 = queueb + (size_t)(bcol + 128 + sr) * DDIM + s * 8;
  const int wofs = w * 512;                             // wave's elem base within half

  // read-side frag elem offsets (slot = inverse swizzle, 2-way bank aliasing = free)
  const int slot = ((lg + ((li >> 1) & 3)) & 3) * 8;
  int aoff[8], boff[4];
  #pragma unroll
  for (int m = 0; m < 8; m++) aoff[m] = wr * 4096 + (m * 16 + li) * 32 + slot;
  #pragma unroll
  for (int n = 0; n < 4; n++) boff[n] = (wc >> 1) * 4096 + ((wc & 1) * 64 + n * 16 + li) * 32 + slot;

  f32x4_t acc[8][4] = {};

  auto stA = [&](int buf, int t) {
    __builtin_amdgcn_global_load_lds((gas_ptr)(gA0 + t * 32), (las_ptr)&Ab[buf][wofs], 16, 0, 0);
    __builtin_amdgcn_global_load_lds((gas_ptr)(gA1 + t * 32), (las_ptr)&Ab[buf][4096 + wofs], 16, 0, 0);
  };
  auto stB = [&](int buf, int t) {
    __builtin_amdgcn_global_load_lds((gas_ptr)(gB0 + t * 32), (las_ptr)&Bb[buf][wofs], 16, 0, 0);
    __builtin_amdgcn_global_load_lds((gas_ptr)(gB1 + t * 32), (las_ptr)&Bb[buf][4096 + wofs], 16, 0, 0);
  };

  // prologue: stage tiles 0,1,2; wait until tile 0 landed (newest 8 = tiles 1,2)
  stA(0, 0); stB(0, 0); stA(1, 1); stB(1, 1); stA(2, 2); stB(2, 2);
  asm volatile("s_waitcnt vmcnt(8)" ::: "memory");
  __builtin_amdgcn_s_barrier();

  #pragma unroll
  for (int t = 0; t < 16; t++) {
    const int rb = t & 3;
    // ---- phase 1: quadrant m=0..3 ----
    bf16x8_t bfr[4], af[4];
    #pragma unroll
    for (int n = 0; n < 4; n++) bfr[n] = *reinterpret_cast<const bf16x8_t*>(&Bb[rb][boff[n]]);
    #pragma unroll
    for (int m = 0; m < 4; m++) af[m] = *reinterpret_cast<const bf16x8_t*>(&Ab[rb][aoff[m]]);
    if (t < 13) stA((t + 3) & 3, t + 3);
    __builtin_amdgcn_s_barrier();
    __builtin_amdgcn_s_setprio(1);
    #pragma unroll
    for (int m = 0; m < 4; m++)
      #pragma unroll
      for (int n = 0; n < 4; n++)
        acc[m][n] = __builtin_amdgcn_mfma_f32_16x16x32_bf16(af[m], bfr[n], acc[m][n], 0, 0, 0);
    __builtin_amdgcn_s_setprio(0);
    __builtin_amdgcn_s_barrier();
    // ---- phase 2: quadrant m=4..7 + K-tile boundary ----
    bf16x8_t af2[4];
    #pragma unroll
    for (int m = 0; m < 4; m++) af2[m] = *reinterpret_cast<const bf16x8_t*>(&Ab[rb][aoff[4 + m]]);
    if (t < 13) stB((t + 3) & 3, t + 3);
    if (t <= 12)      { asm volatile("s_waitcnt vmcnt(8)" ::: "memory"); }
    else if (t == 13) { asm volatile("s_waitcnt vmcnt(4)" ::: "memory"); }
    else if (t == 14) { asm volatile("s_waitcnt vmcnt(0)" ::: "memory"); }
    __builtin_amdgcn_s_barrier();
    __builtin_amdgcn_s_setprio(1);
    #pragma unroll
    for (int m = 0; m < 4; m++)
      #pragma unroll
      for (int n = 0; n < 4; n++)
        acc[4 + m][n] = __builtin_amdgcn_mfma_f32_16x16x32_bf16(af2[m], bfr[n], acc[4 + m][n], 0, 0, 0);
    __builtin_amdgcn_s_setprio(0);
    __builtin_amdgcn_s_barrier();
  }

  // epilogue: per-row argmax over this block's 256 cols (wave owns 64 cols)
  #pragma unroll
  for (int m = 0; m < 8; m++) {
    #pragma unroll
    for (int j = 0; j < 4; j++) {
      u64 best = 0;
      #pragma unroll
      for (int n = 0; n < 4; n++) {
        float v = acc[m][n][j];
        u32 col = (u32)(bcol + wc * 64 + n * 16 + li);
        u64 key = ((u64)fkey(v) << 32) | (u64)(0xFFFFFFFFu - col);
        best = best > key ? best : key;
      }
      #pragma unroll
      for (int off = 1; off < 16; off <<= 1) {
        u64 o = __shfl_xor(best, off);
        best = best > o ? best : o;
      }
      if (li == 0) {
        int row = brow + wr * 128 + m * 16 + lg * 4 + j;
        part[(size_t)row * 512 + (qt * 4 + wc)] = best;
      }
    }
  }
}

// ---------------- kernel 3: reduce argmax partials -> nn_idx ----------------
__global__ void k_argmax_reduce(const u64* __restrict__ part, int* __restrict__ nnidx) {
  int row = (int)((blockIdx.x * blockDim.x + threadIdx.x) >> 6);
  int lane = threadIdx.x & 63;
  const u64* p = part + (size_t)row * 512;
  u64 best = 0;
  #pragma unroll
  for (int i = 0; i < 8; i++) { u64 v = p[lane * 8 + i]; best = best > v ? best : v; }
  #pragma unroll
  for (int off = 1; off < 64; off <<= 1) { u64 o = __shfl_xor(best, off); best = best > o ? best : o; }
  if (lane == 0) nnidx[row] = (int)(0xFFFFFFFFu - (u32)(best & 0xFFFFFFFFu));
}

// ---------------- kernel 4: sim = nn_feats @ features^T / T, fused lse + positives ----
__global__ __launch_bounds__(512, 2) void k_sim_gemm(
    const u16* __restrict__ featb, const u16* __restrict__ queueb,
    const int* __restrict__ nnidx,
    float2* __restrict__ lsep, float* __restrict__ pos) {
  __shared__ u16 A0[8192], A1[8192], A2[8192], A3[8192];
  __shared__ u16 B0[8192], B1[8192], B2[8192], B3[8192];
  u16* const Ab[4] = {A0, A1, A2, A3};
  u16* const Bb[4] = {B0, B1, B2, B3};
  const int tid = threadIdx.x;
  const int w = tid >> 6, lane = tid & 63;
  const int wr = w >> 2, wc = w & 3;
  const int li = lane & 15, lg = lane >> 4;
  // XCD swizzle: 256 blocks = 8 x 32
  const int bid = (int)blockIdx.x;
  const int wg = (bid & 7) * 32 + (bid >> 3);
  const int mt = wg & 15, ct = wg >> 4;
  const int brow = mt * 256, bcol = ct * 256;

  const int sr = tid >> 2;
  const int s  = ((tid & 3) - ((tid >> 3) & 3)) & 3;
  const int r0i = nnidx[brow + sr];
  const int r1i = nnidx[brow + 128 + sr];
  const u16* gA0 = queueb + (size_t)r0i * DDIM + s * 8;   // gathered NN rows
  const u16* gA1 = queueb + (size_t)r1i * DDIM + s * 8;
  const u16* gB0 = featb  + (size_t)(bcol + sr) * DDIM + s * 8;
  const u16* gB1 = featb  + (size_t)(bcol + 128 + sr) * DDIM + s * 8;
  const int wofs = w * 512;

  const int slot = ((lg + ((li >> 1) & 3)) & 3) * 8;
  int aoff[8], boff[4];
  #pragma unroll
  for (int m = 0; m < 8; m++) aoff[m] = wr * 4096 + (m * 16 + li) * 32 + slot;
  #pragma unroll
  for (int n = 0; n < 4; n++) boff[n] = (wc >> 1) * 4096 + ((wc & 1) * 64 + n * 16 + li) * 32 + slot;

  f32x4_t acc[8][4] = {};

  auto stA = [&](int buf, int t) {
    __builtin_amdgcn_global_load_lds((gas_ptr)(gA0 + t * 32), (las_ptr)&Ab[buf][wofs], 16, 0, 0);
    __builtin_amdgcn_global_load_lds((gas_ptr)(gA1 + t * 32), (las_ptr)&Ab[buf][4096 + wofs], 16, 0, 0);
  };
  auto stB = [&](int buf, int t) {
    __builtin_amdgcn_global_load_lds((gas_ptr)(gB0 + t * 32), (las_ptr)&Bb[buf][wofs], 16, 0, 0);
    __builtin_amdgcn_global_load_lds((gas_ptr)(gB1 + t * 32), (las_ptr)&Bb[buf][4096 + wofs], 16, 0, 0);
  };

  stA(0, 0); stB(0, 0); stA(1, 1); stB(1, 1); stA(2, 2); stB(2, 2);
  asm volatile("s_waitcnt vmcnt(8)" ::: "memory");
  __builtin_amdgcn_s_barrier();

  #pragma unroll
  for (int t = 0; t < 16; t++) {
    const int rb = t & 3;
    bf16x8_t bfr[4], af[4];
    #pragma unroll
    for (int n = 0; n < 4; n++) bfr[n] = *reinterpret_cast<const bf16x8_t*>(&Bb[rb][boff[n]]);
    #pragma unroll
    for (int m = 0; m < 4; m++) af[m] = *reinterpret_cast<const bf16x8_t*>(&Ab[rb][aoff[m]]);
    if (t < 13) stA((t + 3) & 3, t + 3);
    __builtin_amdgcn_s_barrier();
    __builtin_amdgcn_s_setprio(1);
    #pragma unroll
    for (int m = 0; m < 4; m++)
      #pragma unroll
      for (int n = 0; n < 4; n++)
        acc[m][n] = __builtin_amdgcn_mfma_f32_16x16x32_bf16(af[m], bfr[n], acc[m][n], 0, 0, 0);
    __builtin_amdgcn_s_setprio(0);
    __builtin_amdgcn_s_barrier();
    bf16x8_t af2[4];
    #pragma unroll
    for (int m = 0; m < 4; m++) af2[m] = *reinterpret_cast<const bf16x8_t*>(&Ab[rb][aoff[4 + m]]);
    if (t < 13) stB((t + 3) & 3, t + 3);
    if (t <= 12)      { asm volatile("s_waitcnt vmcnt(8)" ::: "memory"); }
    else if (t == 13) { asm volatile("s_waitcnt vmcnt(4)" ::: "memory"); }
    else if (t == 14) { asm volatile("s_waitcnt vmcnt(0)" ::: "memory"); }
    __builtin_amdgcn_s_barrier();
    __builtin_amdgcn_s_setprio(1);
    #pragma unroll
    for (int m = 0; m < 4; m++)
      #pragma unroll
      for (int n = 0; n < 4; n++)
        acc[4 + m][n] = __builtin_amdgcn_mfma_f32_16x16x32_bf16(af2[m], bfr[n], acc[4 + m][n], 0, 0, 0);
    __builtin_amdgcn_s_setprio(0);
    __builtin_amdgcn_s_barrier();
  }

  // epilogue: scale by 1/T=2, positives, diag mask, per-row (max, sumexp) over 64 cols
  #pragma unroll
  for (int m = 0; m < 8; m++) {
    #pragma unroll
    for (int j = 0; j < 4; j++) {
      int row = brow + wr * 128 + m * 16 + lg * 4 + j;
      float vals[4];
      float vmax = -3.0e38f;
      #pragma unroll
      for (int n = 0; n < 4; n++) {
        int col = bcol + wc * 64 + n * 16 + li;
        float v = acc[m][n][j] * 2.0f;
        if (col == (row ^ NHALF)) pos[row] = v;   // positive sample (unique writer)
        if (col == row) v = -1.0e30f;             // diag mask
        vals[n] = v;
        vmax = fmaxf(vmax, v);
      }
      float sum = 0.f;
      #pragma unroll
      for (int n = 0; n < 4; n++) sum += __expf(vals[n] - vmax);
      #pragma unroll
      for (int off = 1; off < 16; off <<= 1) {
        float mo = __shfl_xor(vmax, off);
        float so = __shfl_xor(sum, off);
        float M = fmaxf(vmax, mo);
        sum = sum * __expf(vmax - M) + so * __expf(mo - M);
        vmax = M;
      }
      if (li == 0) lsep[(size_t)row * 64 + (ct * 4 + wc)] = make_float2(vmax, sum);
    }
  }
}

// ---------------- kernel 5: per-row logsumexp merge ----------------
__global__ void k_lse(const float2* __restrict__ lsep, float* __restrict__ lse) {
  int row = (int)((blockIdx.x * blockDim.x + threadIdx.x) >> 6);
  int lane = threadIdx.x & 63;
  float2 p = lsep[(size_t)row * 64 + lane];
  float m = p.x, s = p.y;
  #pragma unroll
  for (int off = 1; off < 64; off <<= 1) {
    float mo = __shfl_xor(m, off), so = __shfl_xor(s, off);
    float M = fmaxf(m, mo);
    s = s * __expf(m - M) + so * __expf(mo - M);
    m = M;
  }
  if (lane == 0) lse[row] = m + __logf(s);
}

// ---------------- kernel 6: final scalar ----------------
__global__ void k_final(const float* __restrict__ lse, const float* __restrict__ pos,
                        float* __restrict__ out) {
  __shared__ float red[4];
  int tid = threadIdx.x;
  float a = 0.f;
  for (int i = tid; i < NFEAT; i += 256) a += lse[i] - pos[i];
  #pragma unroll
  for (int off = 32; off >= 1; off >>= 1) a += __shfl_xor(a, off);
  if ((tid & 63) == 0) red[tid >> 6] = a;
  __syncthreads();
  if (tid == 0) out[0] = (red[0] + red[1] + red[2] + red[3]) / (float)NFEAT;
}

extern "C" void kernel_launch(void* const* d_in, const int* in_sizes, int n_in,
                              void* d_out, int out_size, void* d_ws, size_t ws_size,
                              hipStream_t stream) {
  const float* zi    = (const float*)d_in[0];
  const float* zj    = (const float*)d_in[1];
  const float* queue = (const float*)d_in[2];
  float* out = (float*)d_out;
  char* ws = (char*)d_ws;

  // ws layout (bytes):
  u16*    queueb = (u16*)(ws + 0);               // 32768*512*2 = 33554432
  u16*    featb  = (u16*)(ws + 33554432);        // 4096*512*2  = 4194304
  u64*    part   = (u64*)(ws + 37748736);        // 4096*512*8  = 16777216
  int*    nnidx  = (int*)(ws + 54525952);        // 4096*4      = 16384
  float2* lsep   = (float2*)(ws + 54542336);     // 4096*64*8   = 2097152
  float*  pos    = (float*)(ws + 56639488);      // 4096*4      = 16384
  float*  lse    = (float*)(ws + 56655872);      // 4096*4      = 16384
  // total = 56672256 bytes (~54 MB)

  k_norm<<<9216, 256, 0, stream>>>(zi, zj, queue, featb, queueb);
  k_argmax_gemm<<<2048, 512, 0, stream>>>(featb, queueb, part);
  k_argmax_reduce<<<1024, 256, 0, stream>>>(part, nnidx);
  k_sim_gemm<<<256, 512, 0, stream>>>(featb, queueb, nnidx, lsep, pos);
  k_lse<<<1024, 256, 0, stream>>>(lsep, lse);
  k_final<<<1, 256, 0, stream>>>(lse, pos, out);
}